// Round 2
// baseline (330.895 us; speedup 1.0000x reference)
//
#include <hip/hip_runtime.h>

#define NSET 48
#define NITEM 128
#define DIM 256
#define HEADS 4
#define NROWS (NSET * NITEM)   // 6144 rows per source

typedef _Float16 f16;
typedef _Float16 f16x8 __attribute__((ext_vector_type(8)));
typedef _Float16 f16x4 __attribute__((ext_vector_type(4)));
typedef float    f32x4 __attribute__((ext_vector_type(4)));

// ---- workspace layout (bytes) ----
// XYN  f16[12288][256] @ 0         normalized rows (x rows 0..6143, y rows 6144..12287)
// XYH  f16[12288][256] @ 0x600000  raw fp16 rows
// WT   f16[256][256]   @ 0xC00000  W transposed: WT[c][d] = W[d][c]
// LXY  f16[12288][256] @ 0xC20000  projected rows (head h = cols h*64..h*64+63)
static constexpr size_t OFF_XYH = 6291456;
static constexpr size_t OFF_WT  = 12582912;
static constexpr size_t OFF_LXY = 12713984;

// ---------------- prep: W transpose + fp16 ----------------
__global__ __launch_bounds__(256) void k_wt(const float* __restrict__ W,
                                            f16* __restrict__ WT) {
  int c = blockIdx.x, d = threadIdx.x;
  WT[c * DIM + d] = (f16)W[d * DIM + c];
}

// ---------------- prep: row l2-normalize + fp16 casts ----------------
__global__ __launch_bounds__(256) void k_norm(const float* __restrict__ x,
                                              const float* __restrict__ y,
                                              f16* __restrict__ XYN,
                                              f16* __restrict__ XYH) {
  int row  = blockIdx.x * 4 + (threadIdx.x >> 6);   // one wave per 256-elem row
  int lane = threadIdx.x & 63;
  const float* src = (row < NROWS) ? (x + (size_t)row * DIM)
                                   : (y + (size_t)(row - NROWS) * DIM);
  float4 v = *(const float4*)(src + lane * 4);
  float ss = v.x * v.x + v.y * v.y + v.z * v.z + v.w * v.w;
  #pragma unroll
  for (int off = 32; off >= 1; off >>= 1) ss += __shfl_xor(ss, off);
  float rn = 1.0f / sqrtf(fmaxf(ss, 1e-12f));       // tf.nn.l2_normalize semantics
  f16x4 hn = { (f16)(v.x * rn), (f16)(v.y * rn), (f16)(v.z * rn), (f16)(v.w * rn) };
  f16x4 hr = { (f16)v.x, (f16)v.y, (f16)v.z, (f16)v.w };
  *(f16x4*)(XYN + (size_t)row * DIM + lane * 4) = hn;
  *(f16x4*)(XYH + (size_t)row * DIM + lane * 4) = hr;
}

// ---------------- prep: projection GEMM  LXY[R][c] = XYH[R][:] . WT[c][:] ----------------
// No LDS: fragments loaded global->VGPR (tiles are L2-resident).
// Operands: A = WT rows (c), B = XYH rows (R)  =>  D[row=c][col=R], so each
// lane holds 4 consecutive c at fixed R -> vector f16x4 store into LXY[R][c].
__global__ __launch_bounds__(256, 4) void k_proj(const f16* __restrict__ XYH,
                                                 const f16* __restrict__ WT,
                                                 f16* __restrict__ LXY) {
  const int bid = blockIdx.x, rt = bid >> 1, ct = bid & 1;   // 96 row-tiles x 2 col-tiles
  const int tid = threadIdx.x, w = tid >> 6, lane = tid & 63;
  const int wR = (w >> 1) * 64;        // R range within 128-row tile
  const int wC = (w & 1) * 64;         // c range within 128-col tile
  const int la = lane & 15, lb = lane >> 4;

  const f16* pa[4];
  const f16* pb[4];
  #pragma unroll
  for (int m = 0; m < 4; ++m)
    pa[m] = WT + (size_t)(ct * 128 + wC + m * 16 + la) * DIM + (lb << 3);
  #pragma unroll
  for (int n = 0; n < 4; ++n)
    pb[n] = XYH + (size_t)(rt * 128 + wR + n * 16 + la) * DIM + (lb << 3);

  f32x4 acc[4][4] = {};
  #pragma unroll
  for (int k0 = 0; k0 < DIM; k0 += 32) {
    f16x8 a[4], b[4];
    #pragma unroll
    for (int m = 0; m < 4; ++m) a[m] = *(const f16x8*)(pa[m] + k0);
    #pragma unroll
    for (int n = 0; n < 4; ++n) b[n] = *(const f16x8*)(pb[n] + k0);
    #pragma unroll
    for (int m = 0; m < 4; ++m)
      #pragma unroll
      for (int n = 0; n < 4; ++n)
        acc[m][n] = __builtin_amdgcn_mfma_f32_16x16x32_f16(a[m], b[n], acc[m][n], 0, 0, 0);
  }
  #pragma unroll
  for (int m = 0; m < 4; ++m)          // c tiles (row dim of D)
    #pragma unroll
    for (int n = 0; n < 4; ++n) {      // R tiles (col dim of D)
      int R = rt * 128 + wR + n * 16 + la;
      int c = ct * 128 + wC + m * 16 + lb * 4;
      f16x4 hv = { (f16)acc[m][n][0], (f16)acc[m][n][1],
                   (f16)acc[m][n][2], (f16)acc[m][n][3] };
      *(f16x4*)(LXY + (size_t)R * DIM + c) = hv;
    }
}

// ---------------- main: per (y,x) pair -> cos_sim tile + score ----------------
// No LDS. Phase-1 operands swapped (A = y rows j, B = x rows i) so D[j][i]:
// each lane holds 4 consecutive j at fixed i -> f32x4 store to out0[i*128+j].
__global__ __launch_bounds__(256, 4) void k_main(const f16* __restrict__ XYN,
                                                 const f16* __restrict__ LXY,
                                                 const float* __restrict__ nItem,
                                                 const float* __restrict__ w2,
                                                 float* __restrict__ out0,
                                                 float* __restrict__ out1) {
  __shared__ float red[4][4];
  const int bid = blockIdx.x;
  const int ys = bid / NSET, xs = bid % NSET;   // x fastest: y-set data stays hot in L2
  const int tid = threadIdx.x, w = tid >> 6, lane = tid & 63;
  const int wj = (w >> 1) * 64;        // j (y item) range -> A operand
  const int wi = (w & 1) * 64;         // i (x item) range -> B operand
  const int la = lane & 15, lb = lane >> 4;

  // ---- phase 1: cos_sim[y, x, i, j] = xn[x,i,:] . yn[y,j,:] ----
  {
    const f16* ybase = XYN + (size_t)(NROWS + ys * NITEM) * DIM;
    const f16* xbase = XYN + (size_t)(xs * NITEM) * DIM;
    const f16* pa[4];
    const f16* pb[4];
    #pragma unroll
    for (int m = 0; m < 4; ++m)
      pa[m] = ybase + (size_t)(wj + m * 16 + la) * DIM + (lb << 3);
    #pragma unroll
    for (int n = 0; n < 4; ++n)
      pb[n] = xbase + (size_t)(wi + n * 16 + la) * DIM + (lb << 3);

    f32x4 acc[4][4] = {};
    #pragma unroll
    for (int k0 = 0; k0 < DIM; k0 += 32) {
      f16x8 a[4], b[4];
      #pragma unroll
      for (int m = 0; m < 4; ++m) a[m] = *(const f16x8*)(pa[m] + k0);
      #pragma unroll
      for (int n = 0; n < 4; ++n) b[n] = *(const f16x8*)(pb[n] + k0);
      #pragma unroll
      for (int m = 0; m < 4; ++m)
        #pragma unroll
        for (int n = 0; n < 4; ++n)
          acc[m][n] = __builtin_amdgcn_mfma_f32_16x16x32_f16(a[m], b[n], acc[m][n], 0, 0, 0);
    }
    float* base = out0 + (size_t)(ys * NSET + xs) * NITEM * NITEM;
    #pragma unroll
    for (int m = 0; m < 4; ++m)
      #pragma unroll
      for (int n = 0; n < 4; ++n) {
        int i  = wi + n * 16 + la;
        int j0 = wj + m * 16 + lb * 4;
        *(f32x4*)(base + (size_t)i * NITEM + j0) = acc[m][n];
      }
  }

  // ---- phase 2: scores. s[h] = sum_ij relu(lx[i,h*64:].ly[j,h*64:]) ----
  {
    const f16* ybase = LXY + (size_t)(NROWS + ys * NITEM) * DIM;
    const f16* xbase = LXY + (size_t)(xs * NITEM) * DIM;
    const f16* pa[4];
    const f16* pb[4];
    #pragma unroll
    for (int m = 0; m < 4; ++m)
      pa[m] = ybase + (size_t)(wj + m * 16 + la) * DIM + (lb << 3);
    #pragma unroll
    for (int n = 0; n < 4; ++n)
      pb[n] = xbase + (size_t)(wi + n * 16 + la) * DIM + (lb << 3);

    float rsum[HEADS];
    #pragma unroll
    for (int h = 0; h < HEADS; ++h) {
      f32x4 acc[4][4] = {};
      #pragma unroll
      for (int kk = 0; kk < 2; ++kk) {           // K=64 per head; relu AFTER full K
        int k0 = h * 64 + kk * 32;
        f16x8 a[4], b[4];
        #pragma unroll
        for (int m = 0; m < 4; ++m) a[m] = *(const f16x8*)(pa[m] + k0);
        #pragma unroll
        for (int n = 0; n < 4; ++n) b[n] = *(const f16x8*)(pb[n] + k0);
        #pragma unroll
        for (int m = 0; m < 4; ++m)
          #pragma unroll
          for (int n = 0; n < 4; ++n)
            acc[m][n] = __builtin_amdgcn_mfma_f32_16x16x32_f16(a[m], b[n], acc[m][n], 0, 0, 0);
      }
      float s = 0.f;
      #pragma unroll
      for (int m = 0; m < 4; ++m)
        #pragma unroll
        for (int n = 0; n < 4; ++n)
          #pragma unroll
          for (int r = 0; r < 4; ++r) s += fmaxf(acc[m][n][r], 0.f);
      rsum[h] = s;
    }
    #pragma unroll
    for (int off = 32; off >= 1; off >>= 1)
      #pragma unroll
      for (int h = 0; h < HEADS; ++h) rsum[h] += __shfl_xor(rsum[h], off);
    if (lane == 0) {
      #pragma unroll
      for (int h = 0; h < HEADS; ++h) red[w][h] = rsum[h];
    }
  }
  __syncthreads();
  if (tid == 0) {
    // relu(S/8) summed == (sum relu(S))/8 ; then / nItem[x] / nItem[y]; then @ w2
    float inv = 1.0f / (8.0f * nItem[xs] * nItem[ys]);
    float sc = 0.f;
    #pragma unroll
    for (int h = 0; h < HEADS; ++h)
      sc += (red[0][h] + red[1][h] + red[2][h] + red[3][h]) * inv * w2[h];
    out1[ys * NSET + xs] = sc;
  }
}

// ---------------- launch ----------------
extern "C" void kernel_launch(void* const* d_in, const int* in_sizes, int n_in,
                              void* d_out, int out_size, void* d_ws, size_t ws_size,
                              hipStream_t stream) {
  const float* x     = (const float*)d_in[0];
  const float* y     = (const float*)d_in[1];
  const float* nItem = (const float*)d_in[2];
  const float* W     = (const float*)d_in[3];
  const float* w2    = (const float*)d_in[4];
  float* out0 = (float*)d_out;
  float* out1 = out0 + (size_t)NSET * NSET * NITEM * NITEM;

  char* ws = (char*)d_ws;
  f16* XYN = (f16*)ws;
  f16* XYH = (f16*)(ws + OFF_XYH);
  f16* WT  = (f16*)(ws + OFF_WT);
  f16* LXY = (f16*)(ws + OFF_LXY);

  k_wt<<<256, 256, 0, stream>>>(W, WT);
  k_norm<<<(2 * NROWS) / 4, 256, 0, stream>>>(x, y, XYN, XYH);
  k_proj<<<192, 256, 0, stream>>>(XYH, WT, LXY);
  k_main<<<NSET * NSET, 256, 0, stream>>>(XYN, LXY, nItem, w2, out0, out1);
}

// Round 3
// 304.783 us; speedup vs baseline: 1.0857x; 1.0857x over previous
//
#include <hip/hip_runtime.h>

#define NSET 48
#define NITEM 128
#define DIM 256
#define HEADS 4
#define NROWS (NSET * NITEM)   // 6144 rows per source

typedef _Float16 f16;
typedef _Float16 f16x8 __attribute__((ext_vector_type(8)));
typedef _Float16 f16x4 __attribute__((ext_vector_type(4)));
typedef float    f32x4 __attribute__((ext_vector_type(4)));

// ---- workspace layout (bytes) ----
static constexpr size_t OFF_XYH = 6291456;
static constexpr size_t OFF_WT  = 12582912;
static constexpr size_t OFF_LXY = 12713984;

// ---------------- prep: W transpose + fp16 ----------------
__global__ __launch_bounds__(256) void k_wt(const float* __restrict__ W,
                                            f16* __restrict__ WT) {
  int c = blockIdx.x, d = threadIdx.x;
  WT[c * DIM + d] = (f16)W[d * DIM + c];
}

// ---------------- prep: row l2-normalize + fp16 casts ----------------
__global__ __launch_bounds__(256) void k_norm(const float* __restrict__ x,
                                              const float* __restrict__ y,
                                              f16* __restrict__ XYN,
                                              f16* __restrict__ XYH) {
  int row  = blockIdx.x * 4 + (threadIdx.x >> 6);   // one wave per 256-elem row
  int lane = threadIdx.x & 63;
  const float* src = (row < NROWS) ? (x + (size_t)row * DIM)
                                   : (y + (size_t)(row - NROWS) * DIM);
  float4 v = *(const float4*)(src + lane * 4);
  float ss = v.x * v.x + v.y * v.y + v.z * v.z + v.w * v.w;
  #pragma unroll
  for (int off = 32; off >= 1; off >>= 1) ss += __shfl_xor(ss, off);
  float rn = 1.0f / sqrtf(fmaxf(ss, 1e-12f));       // tf.nn.l2_normalize semantics
  f16x4 hn = { (f16)(v.x * rn), (f16)(v.y * rn), (f16)(v.z * rn), (f16)(v.w * rn) };
  f16x4 hr = { (f16)v.x, (f16)v.y, (f16)v.z, (f16)v.w };
  *(f16x4*)(XYN + (size_t)row * DIM + lane * 4) = hn;
  *(f16x4*)(XYH + (size_t)row * DIM + lane * 4) = hr;
}

// ---------------- prep: projection GEMM  LXY[R][c] = XYH[R][:] . WT[c][:] ----------------
// No LDS: fragments loaded global->VGPR (tiles are L2-resident).
// A = WT rows (c), B = XYH rows (R) => D[row=c][col=R]; lane holds 4
// consecutive c at fixed R -> vector f16x4 store into LXY[R][c].
__global__ __launch_bounds__(256, 4) void k_proj(const f16* __restrict__ XYH,
                                                 const f16* __restrict__ WT,
                                                 f16* __restrict__ LXY) {
  const int bid = blockIdx.x, rt = bid >> 1, ct = bid & 1;   // 96 row-tiles x 2 col-tiles
  const int tid = threadIdx.x, w = tid >> 6, lane = tid & 63;
  const int wR = (w >> 1) * 64;        // R range within 128-row tile
  const int wC = (w & 1) * 64;         // c range within 128-col tile
  const int la = lane & 15, lb = lane >> 4;

  const f16* pa[4];
  const f16* pb[4];
  #pragma unroll
  for (int m = 0; m < 4; ++m)
    pa[m] = WT + (size_t)(ct * 128 + wC + m * 16 + la) * DIM + (lb << 3);
  #pragma unroll
  for (int n = 0; n < 4; ++n)
    pb[n] = XYH + (size_t)(rt * 128 + wR + n * 16 + la) * DIM + (lb << 3);

  f32x4 acc[4][4] = {};
  #pragma unroll
  for (int k0 = 0; k0 < DIM; k0 += 32) {
    f16x8 a[4], b[4];
    #pragma unroll
    for (int m = 0; m < 4; ++m) a[m] = *(const f16x8*)(pa[m] + k0);
    #pragma unroll
    for (int n = 0; n < 4; ++n) b[n] = *(const f16x8*)(pb[n] + k0);
    #pragma unroll
    for (int m = 0; m < 4; ++m)
      #pragma unroll
      for (int n = 0; n < 4; ++n)
        acc[m][n] = __builtin_amdgcn_mfma_f32_16x16x32_f16(a[m], b[n], acc[m][n], 0, 0, 0);
  }
  #pragma unroll
  for (int m = 0; m < 4; ++m)          // c tiles (row dim of D)
    #pragma unroll
    for (int n = 0; n < 4; ++n) {      // R tiles (col dim of D)
      int R = rt * 128 + wR + n * 16 + la;
      int c = ct * 128 + wC + m * 16 + lb * 4;
      f16x4 hv = { (f16)acc[m][n][0], (f16)acc[m][n][1],
                   (f16)acc[m][n][2], (f16)acc[m][n][3] };
      *(f16x4*)(LXY + (size_t)R * DIM + c) = hv;
    }
}

// ---------------- main: per (y,x) pair -> cos_sim tile + score ----------------
// No LDS reads (inputs L2/L3-resident). out0 stores are NON-TEMPORAL: they
// stream to HBM without L2 write-allocate, avoiding the RMW thrash seen in R2
// (partial-line writes x 1024 concurrent 64KB tiles >> 32MB L2).
__global__ __launch_bounds__(256, 4) void k_main(const f16* __restrict__ XYN,
                                                 const f16* __restrict__ LXY,
                                                 const float* __restrict__ nItem,
                                                 const float* __restrict__ w2,
                                                 float* __restrict__ out0,
                                                 float* __restrict__ out1) {
  __shared__ float red[4][4];
  const int bid = blockIdx.x;
  const int ys = bid / NSET, xs = bid % NSET;   // x fastest: y-set data stays hot in L2
  const int tid = threadIdx.x, w = tid >> 6, lane = tid & 63;
  const int wj = (w >> 1) * 64;        // j (y item) range -> A operand
  const int wi = (w & 1) * 64;         // i (x item) range -> B operand
  const int la = lane & 15, lb = lane >> 4;

  // ---- phase 1: cos_sim[y, x, i, j] = xn[x,i,:] . yn[y,j,:] ----
  {
    const f16* ybase = XYN + (size_t)(NROWS + ys * NITEM) * DIM;
    const f16* xbase = XYN + (size_t)(xs * NITEM) * DIM;
    const f16* pa[4];
    const f16* pb[4];
    #pragma unroll
    for (int m = 0; m < 4; ++m)
      pa[m] = ybase + (size_t)(wj + m * 16 + la) * DIM + (lb << 3);
    #pragma unroll
    for (int n = 0; n < 4; ++n)
      pb[n] = xbase + (size_t)(wi + n * 16 + la) * DIM + (lb << 3);

    f32x4 acc[4][4] = {};
    #pragma unroll
    for (int k0 = 0; k0 < DIM; k0 += 32) {
      f16x8 a[4], b[4];
      #pragma unroll
      for (int m = 0; m < 4; ++m) a[m] = *(const f16x8*)(pa[m] + k0);
      #pragma unroll
      for (int n = 0; n < 4; ++n) b[n] = *(const f16x8*)(pb[n] + k0);
      #pragma unroll
      for (int m = 0; m < 4; ++m)
        #pragma unroll
        for (int n = 0; n < 4; ++n)
          acc[m][n] = __builtin_amdgcn_mfma_f32_16x16x32_f16(a[m], b[n], acc[m][n], 0, 0, 0);
    }
    float* base = out0 + (size_t)(ys * NSET + xs) * NITEM * NITEM;
    #pragma unroll
    for (int m = 0; m < 4; ++m)
      #pragma unroll
      for (int n = 0; n < 4; ++n) {
        int i  = wi + n * 16 + la;
        int j0 = wj + m * 16 + lb * 4;
        __builtin_nontemporal_store(acc[m][n],
                                    (f32x4*)(base + (size_t)i * NITEM + j0));
      }
  }

  // ---- phase 2: scores. s[h] = sum_ij relu(lx[i,h*64:].ly[j,h*64:]) ----
  {
    const f16* ybase = LXY + (size_t)(NROWS + ys * NITEM) * DIM;
    const f16* xbase = LXY + (size_t)(xs * NITEM) * DIM;
    const f16* pa[4];
    const f16* pb[4];
    #pragma unroll
    for (int m = 0; m < 4; ++m)
      pa[m] = ybase + (size_t)(wj + m * 16 + la) * DIM + (lb << 3);
    #pragma unroll
    for (int n = 0; n < 4; ++n)
      pb[n] = xbase + (size_t)(wi + n * 16 + la) * DIM + (lb << 3);

    float rsum[HEADS];
    #pragma unroll
    for (int h = 0; h < HEADS; ++h) {
      f32x4 acc[4][4] = {};
      #pragma unroll
      for (int kk = 0; kk < 2; ++kk) {           // K=64 per head; relu AFTER full K
        int k0 = h * 64 + kk * 32;
        f16x8 a[4], b[4];
        #pragma unroll
        for (int m = 0; m < 4; ++m) a[m] = *(const f16x8*)(pa[m] + k0);
        #pragma unroll
        for (int n = 0; n < 4; ++n) b[n] = *(const f16x8*)(pb[n] + k0);
        #pragma unroll
        for (int m = 0; m < 4; ++m)
          #pragma unroll
          for (int n = 0; n < 4; ++n)
            acc[m][n] = __builtin_amdgcn_mfma_f32_16x16x32_f16(a[m], b[n], acc[m][n], 0, 0, 0);
      }
      float s = 0.f;
      #pragma unroll
      for (int m = 0; m < 4; ++m)
        #pragma unroll
        for (int n = 0; n < 4; ++n)
          #pragma unroll
          for (int r = 0; r < 4; ++r) s += fmaxf(acc[m][n][r], 0.f);
      rsum[h] = s;
    }
    #pragma unroll
    for (int off = 32; off >= 1; off >>= 1)
      #pragma unroll
      for (int h = 0; h < HEADS; ++h) rsum[h] += __shfl_xor(rsum[h], off);
    if (lane == 0) {
      #pragma unroll
      for (int h = 0; h < HEADS; ++h) red[w][h] = rsum[h];
    }
  }
  __syncthreads();
  if (tid == 0) {
    // relu(S/8) summed == (sum relu(S))/8 ; then / nItem[x] / nItem[y]; then @ w2
    float inv = 1.0f / (8.0f * nItem[xs] * nItem[ys]);
    float sc = 0.f;
    #pragma unroll
    for (int h = 0; h < HEADS; ++h)
      sc += (red[0][h] + red[1][h] + red[2][h] + red[3][h]) * inv * w2[h];
    out1[ys * NSET + xs] = sc;
  }
}

// ---------------- launch ----------------
extern "C" void kernel_launch(void* const* d_in, const int* in_sizes, int n_in,
                              void* d_out, int out_size, void* d_ws, size_t ws_size,
                              hipStream_t stream) {
  const float* x     = (const float*)d_in[0];
  const float* y     = (const float*)d_in[1];
  const float* nItem = (const float*)d_in[2];
  const float* W     = (const float*)d_in[3];
  const float* w2    = (const float*)d_in[4];
  float* out0 = (float*)d_out;
  float* out1 = out0 + (size_t)NSET * NSET * NITEM * NITEM;

  char* ws = (char*)d_ws;
  f16* XYN = (f16*)ws;
  f16* XYH = (f16*)(ws + OFF_XYH);
  f16* WT  = (f16*)(ws + OFF_WT);
  f16* LXY = (f16*)(ws + OFF_LXY);

  k_wt<<<256, 256, 0, stream>>>(W, WT);
  k_norm<<<(2 * NROWS) / 4, 256, 0, stream>>>(x, y, XYN, XYH);
  k_proj<<<192, 256, 0, stream>>>(XYH, WT, LXY);
  k_main<<<NSET * NSET, 256, 0, stream>>>(XYN, LXY, nItem, w2, out0, out1);
}